// Round 1
// baseline (432.246 us; speedup 1.0000x reference)
//
#include <hip/hip_runtime.h>

#define N_NODES 50000
#define N_EDGES 800000
#define F_INPUT 256
#define HDIM 64
#define NCLS 10
#define NGRAPH 64

// ---------------- degree histogram ----------------
__global__ __launch_bounds__(256) void k_deg_count(const int* __restrict__ dst,
                                                   int* __restrict__ degi, int E) {
    int e = blockIdx.x * 256 + threadIdx.x;
    if (e < E) atomicAdd(&degi[dst[e]], 1);
}

// dis = rsqrt(deg+1), selfn = 1/(deg+1)
__global__ __launch_bounds__(256) void k_norm(const int* __restrict__ degi,
                                              float* __restrict__ dis,
                                              float* __restrict__ selfn, int n) {
    int i = blockIdx.x * 256 + threadIdx.x;
    if (i < n) {
        float d = (float)(degi[i] + 1);
        dis[i] = rsqrtf(d);
        selfn[i] = 1.0f / d;
    }
}

// ---------------- prefix sum (3-phase) ----------------
__global__ __launch_bounds__(256) void k_scan1(const int* __restrict__ degi,
                                               int* __restrict__ off,
                                               int* __restrict__ bsum, int n) {
    __shared__ int tmp[256];
    int t = threadIdx.x;
    int i = blockIdx.x * 256 + t;
    int v = (i < n) ? degi[i] : 0;
    tmp[t] = v;
    __syncthreads();
    for (int d = 1; d < 256; d <<= 1) {
        int x = (t >= d) ? tmp[t - d] : 0;
        __syncthreads();
        tmp[t] += x;
        __syncthreads();
    }
    if (i < n) off[i] = tmp[t] - v;        // exclusive within block
    if (t == 255) bsum[blockIdx.x] = tmp[t];
}

__global__ __launch_bounds__(256) void k_scan2(int* __restrict__ bsum, int nb) {
    __shared__ int tmp[256];
    int t = threadIdx.x;
    int v = (t < nb) ? bsum[t] : 0;
    tmp[t] = v;
    __syncthreads();
    for (int d = 1; d < 256; d <<= 1) {
        int x = (t >= d) ? tmp[t - d] : 0;
        __syncthreads();
        tmp[t] += x;
        __syncthreads();
    }
    if (t < nb) bsum[t] = tmp[t] - v;      // exclusive block bases
}

__global__ __launch_bounds__(256) void k_scan3(int* __restrict__ off,
                                               int* __restrict__ cur,
                                               const int* __restrict__ bsum, int n) {
    int i = blockIdx.x * 256 + threadIdx.x;
    if (i < n) {
        int o = off[i] + bsum[blockIdx.x];
        off[i] = o;
        cur[i] = o;
    }
}

// scatter edges into CSR buckets (order within bucket nondeterministic — fp sum
// order differences are ~1e-6, far under threshold)
__global__ __launch_bounds__(256) void k_fill(const int* __restrict__ src,
                                              const int* __restrict__ dst,
                                              const float* __restrict__ dis,
                                              int* __restrict__ cur,
                                              int* __restrict__ eidx,
                                              float* __restrict__ ew, int E) {
    int e = blockIdx.x * 256 + threadIdx.x;
    if (e < E) {
        int s = src[e], d = dst[e];
        int p = atomicAdd(&cur[d], 1);
        eidx[p] = s;
        ew[p] = dis[s] * dis[d];
    }
}

// ---------------- fp32 GEMM: C[n,64] = A[n,K] @ B[K,64] ----------------
// 128x64 tile, 256 threads, 4 rows x 8 cols per thread, K staged in 64-chunks.
template <int K>
__global__ __launch_bounds__(256) void k_gemm(const float* __restrict__ A,
                                              const float* __restrict__ B,
                                              float* __restrict__ C, int n) {
    __shared__ float As[128][70];   // pad 70: bank-stride 6 -> broadcast reads ~free
    __shared__ float Bs[64][64];
    const int tid = threadIdx.x;
    const int row0 = blockIdx.x * 128;
    const int tr = (tid >> 3) * 4;   // 0..124
    const int tc = (tid & 7) * 8;    // 0..56
    const int lr = tid >> 4;         // 0..15
    const int lk = (tid & 15) * 4;   // 0..60

    float acc[4][8];
#pragma unroll
    for (int i = 0; i < 4; ++i)
#pragma unroll
        for (int j = 0; j < 8; ++j) acc[i][j] = 0.0f;

    for (int kc = 0; kc < K; kc += 64) {
#pragma unroll
        for (int rr = 0; rr < 8; ++rr) {
            int r = lr + rr * 16;
            int grow = row0 + r;
            float4 v = make_float4(0.f, 0.f, 0.f, 0.f);
            if (grow < n) v = *(const float4*)(A + (size_t)grow * K + kc + lk);
            *(float4*)&As[r][lk] = v;
        }
#pragma unroll
        for (int rr = 0; rr < 4; ++rr) {
            int kk = lr + rr * 16;
            *(float4*)&Bs[kk][lk] = *(const float4*)(B + (size_t)(kc + kk) * HDIM + lk);
        }
        __syncthreads();
#pragma unroll 8
        for (int k = 0; k < 64; ++k) {
            float aa[4];
#pragma unroll
            for (int i = 0; i < 4; ++i) aa[i] = As[tr + i][k];
            float4 b0 = *(const float4*)&Bs[k][tc];
            float4 b1 = *(const float4*)&Bs[k][tc + 4];
            float bb[8] = {b0.x, b0.y, b0.z, b0.w, b1.x, b1.y, b1.z, b1.w};
#pragma unroll
            for (int i = 0; i < 4; ++i)
#pragma unroll
                for (int j = 0; j < 8; ++j) acc[i][j] = fmaf(aa[i], bb[j], acc[i][j]);
        }
        __syncthreads();
    }
#pragma unroll
    for (int i = 0; i < 4; ++i) {
        int grow = row0 + tr + i;
        if (grow < n) {
            *(float4*)(C + (size_t)grow * HDIM + tc) =
                make_float4(acc[i][0], acc[i][1], acc[i][2], acc[i][3]);
            *(float4*)(C + (size_t)grow * HDIM + tc + 4) =
                make_float4(acc[i][4], acc[i][5], acc[i][6], acc[i][7]);
        }
    }
}

// ---------------- pull-style aggregation + self-loop + bias + relu ----------------
// 16 lanes per node, each owns a float4 of the 64-wide feature row.
__global__ __launch_bounds__(256) void k_gather(const float* __restrict__ h,
                                                const int* __restrict__ off,
                                                const int* __restrict__ degi,
                                                const int* __restrict__ eidx,
                                                const float* __restrict__ ew,
                                                const float* __restrict__ selfn,
                                                const float* __restrict__ bias,
                                                float* __restrict__ out, int n) {
    int t = blockIdx.x * 256 + threadIdx.x;
    int i = t >> 4;
    if (i >= n) return;
    int q = (t & 15) * 4;
    int e0 = off[i];
    int e1 = e0 + degi[i];
    float ax = 0.f, ay = 0.f, az = 0.f, aw = 0.f;
    for (int e = e0; e < e1; ++e) {
        int s = eidx[e];
        float w = ew[e];
        float4 v = *(const float4*)(h + (size_t)s * HDIM + q);
        ax = fmaf(v.x, w, ax);
        ay = fmaf(v.y, w, ay);
        az = fmaf(v.z, w, az);
        aw = fmaf(v.w, w, aw);
    }
    float sn = selfn[i];
    float4 hv = *(const float4*)(h + (size_t)i * HDIM + q);
    float4 b = *(const float4*)(bias + q);
    ax = fmaf(hv.x, sn, ax) + b.x;
    ay = fmaf(hv.y, sn, ay) + b.y;
    az = fmaf(hv.z, sn, az) + b.z;
    aw = fmaf(hv.w, sn, aw) + b.w;
    *(float4*)(out + (size_t)i * HDIM + q) =
        make_float4(fmaxf(ax, 0.f), fmaxf(ay, 0.f), fmaxf(az, 0.f), fmaxf(aw, 0.f));
}

// ---------------- per-graph mean pool + linear head ----------------
__global__ __launch_bounds__(256) void k_pool(const float* __restrict__ h,
                                              const int* __restrict__ batch,
                                              const float* __restrict__ linW,
                                              const float* __restrict__ linb,
                                              float* __restrict__ out, int n) {
    __shared__ float part[4][64];
    int g = blockIdx.x;
    int t = threadIdx.x;
    int f = t & 63;
    int rg = t >> 6;
    // lower_bound(batch, g)
    int lo = 0, hi = n;
    while (lo < hi) { int m = (lo + hi) >> 1; if (batch[m] < g) lo = m + 1; else hi = m; }
    int s = lo;
    lo = 0; hi = n;
    while (lo < hi) { int m = (lo + hi) >> 1; if (batch[m] < g + 1) lo = m + 1; else hi = m; }
    int e2 = lo;

    float sum = 0.f;
    for (int i = s + rg; i < e2; i += 4) sum += h[(size_t)i * HDIM + f];
    part[rg][f] = sum;
    __syncthreads();
    if (t < 64) {
        float tot = part[0][t] + part[1][t] + part[2][t] + part[3][t];
        part[0][t] = tot / fmaxf((float)(e2 - s), 1.0f);
    }
    __syncthreads();
    if (t < NCLS) {
        float acc = linb[t];
#pragma unroll
        for (int k = 0; k < 64; ++k) acc = fmaf(part[0][k], linW[k * NCLS + t], acc);
        out[g * NCLS + t] = acc;
    }
}

extern "C" void kernel_launch(void* const* d_in, const int* in_sizes, int n_in,
                              void* d_out, int out_size, void* d_ws, size_t ws_size,
                              hipStream_t stream) {
    (void)in_sizes; (void)n_in; (void)out_size; (void)ws_size;
    const float* x    = (const float*)d_in[0];
    const int*   ei   = (const int*)d_in[1];
    const int*   batch= (const int*)d_in[2];
    const float* W1   = (const float*)d_in[3];
    const float* b1   = (const float*)d_in[4];
    const float* W2   = (const float*)d_in[5];
    const float* b2   = (const float*)d_in[6];
    const float* W3   = (const float*)d_in[7];
    const float* b3   = (const float*)d_in[8];
    const float* linW = (const float*)d_in[9];
    const float* linb = (const float*)d_in[10];
    float* out = (float*)d_out;

    const int N = N_NODES, E = N_EDGES;
    const int* src = ei;
    const int* dst = ei + E;

    char* ws = (char*)d_ws;
    float* hA    = (float*)ws; ws += (size_t)N * HDIM * 4;
    float* hB    = (float*)ws; ws += (size_t)N * HDIM * 4;
    float* dis   = (float*)ws; ws += (size_t)N * 4;
    float* selfn = (float*)ws; ws += (size_t)N * 4;
    float* ew    = (float*)ws; ws += (size_t)E * 4;
    int*   degi  = (int*)ws;   ws += (size_t)N * 4;
    int*   off   = (int*)ws;   ws += (size_t)N * 4;
    int*   cur   = (int*)ws;   ws += (size_t)N * 4;
    int*   eidx  = (int*)ws;   ws += (size_t)E * 4;
    int*   bsum  = (int*)ws;   ws += 256 * 4;

    const int nbN = (N + 255) / 256;   // 196
    const int nbE = (E + 255) / 256;   // 3125
    const int gb  = (N + 127) / 128;   // 391
    const int ngth = (N * 16 + 255) / 256;

    hipMemsetAsync(degi, 0, (size_t)N * 4, stream);
    k_deg_count<<<nbE, 256, 0, stream>>>(dst, degi, E);
    k_norm<<<nbN, 256, 0, stream>>>(degi, dis, selfn, N);
    k_scan1<<<nbN, 256, 0, stream>>>(degi, off, bsum, N);
    k_scan2<<<1, 256, 0, stream>>>(bsum, nbN);
    k_scan3<<<nbN, 256, 0, stream>>>(off, cur, bsum, N);
    k_fill<<<nbE, 256, 0, stream>>>(src, dst, dis, cur, eidx, ew, E);

    // layer 1
    k_gemm<F_INPUT><<<gb, 256, 0, stream>>>(x, W1, hA, N);
    k_gather<<<ngth, 256, 0, stream>>>(hA, off, degi, eidx, ew, selfn, b1, hB, N);
    // layer 2
    k_gemm<HDIM><<<gb, 256, 0, stream>>>(hB, W2, hA, N);
    k_gather<<<ngth, 256, 0, stream>>>(hA, off, degi, eidx, ew, selfn, b2, hB, N);
    // layer 3
    k_gemm<HDIM><<<gb, 256, 0, stream>>>(hB, W3, hA, N);
    k_gather<<<ngth, 256, 0, stream>>>(hA, off, degi, eidx, ew, selfn, b3, hB, N);
    // pool + head
    k_pool<<<NGRAPH, 256, 0, stream>>>(hB, batch, linW, linb, out, N);
}

// Round 2
// 380.335 us; speedup vs baseline: 1.1365x; 1.1365x over previous
//
#include <hip/hip_runtime.h>

#define N_NODES 50000
#define N_EDGES 800000
#define F_INPUT 256
#define HDIM 64
#define NCLS 10
#define NGRAPH 64

// ---------------- degree histogram ----------------
__global__ __launch_bounds__(256) void k_deg_count(const int* __restrict__ dst,
                                                   int* __restrict__ degi, int E) {
    int e = blockIdx.x * 256 + threadIdx.x;
    if (e < E) atomicAdd(&degi[dst[e]], 1);
}

// ---------------- prefix sum (3-phase) ----------------
__global__ __launch_bounds__(256) void k_scan1(const int* __restrict__ degi,
                                               int* __restrict__ off,
                                               int* __restrict__ bsum, int n) {
    __shared__ int tmp[256];
    int t = threadIdx.x;
    int i = blockIdx.x * 256 + t;
    int v = (i < n) ? degi[i] : 0;
    tmp[t] = v;
    __syncthreads();
    for (int d = 1; d < 256; d <<= 1) {
        int x = (t >= d) ? tmp[t - d] : 0;
        __syncthreads();
        tmp[t] += x;
        __syncthreads();
    }
    if (i < n) off[i] = tmp[t] - v;        // exclusive within block
    if (t == 255) bsum[blockIdx.x] = tmp[t];
}

__global__ __launch_bounds__(256) void k_scan2(int* __restrict__ bsum, int nb) {
    __shared__ int tmp[256];
    int t = threadIdx.x;
    int v = (t < nb) ? bsum[t] : 0;
    tmp[t] = v;
    __syncthreads();
    for (int d = 1; d < 256; d <<= 1) {
        int x = (t >= d) ? tmp[t - d] : 0;
        __syncthreads();
        tmp[t] += x;
        __syncthreads();
    }
    if (t < nb) bsum[t] = tmp[t] - v;      // exclusive block bases
}

// scan finalize + GCN norm factors (fused elementwise pass)
__global__ __launch_bounds__(256) void k_scan3(int* __restrict__ off,
                                               int* __restrict__ cur,
                                               const int* __restrict__ bsum,
                                               const int* __restrict__ degi,
                                               float* __restrict__ dis,
                                               float* __restrict__ selfn, int n) {
    int i = blockIdx.x * 256 + threadIdx.x;
    if (i < n) {
        int o = off[i] + bsum[blockIdx.x];
        off[i] = o;
        cur[i] = o;
        float d = (float)(degi[i] + 1);
        dis[i] = rsqrtf(d);
        selfn[i] = 1.0f / d;
    }
}

// scatter edges into CSR buckets; packed (src, weight) as one 8B store to
// halve the number of dirtied cache lines (random 4B stores -> 64B HBM lines)
__global__ __launch_bounds__(256) void k_fill(const int* __restrict__ src,
                                              const int* __restrict__ dst,
                                              const float* __restrict__ dis,
                                              int* __restrict__ cur,
                                              int2* __restrict__ eadj, int E) {
    int e = blockIdx.x * 256 + threadIdx.x;
    if (e < E) {
        int s = src[e], d = dst[e];
        int p = atomicAdd(&cur[d], 1);
        eadj[p] = make_int2(s, __float_as_int(dis[s] * dis[d]));
    }
}

// ---------------- fp32 GEMM: C[n,64] = A[n,K] @ B[K,64] ----------------
template <int K>
__global__ __launch_bounds__(256) void k_gemm(const float* __restrict__ A,
                                              const float* __restrict__ B,
                                              float* __restrict__ C, int n) {
    __shared__ float As[128][70];
    __shared__ float Bs[64][64];
    const int tid = threadIdx.x;
    const int row0 = blockIdx.x * 128;
    const int tr = (tid >> 3) * 4;   // 0..124
    const int tc = (tid & 7) * 8;    // 0..56
    const int lr = tid >> 4;         // 0..15
    const int lk = (tid & 15) * 4;   // 0..60

    float acc[4][8];
#pragma unroll
    for (int i = 0; i < 4; ++i)
#pragma unroll
        for (int j = 0; j < 8; ++j) acc[i][j] = 0.0f;

    for (int kc = 0; kc < K; kc += 64) {
#pragma unroll
        for (int rr = 0; rr < 8; ++rr) {
            int r = lr + rr * 16;
            int grow = row0 + r;
            float4 v = make_float4(0.f, 0.f, 0.f, 0.f);
            if (grow < n) v = *(const float4*)(A + (size_t)grow * K + kc + lk);
            *(float4*)&As[r][lk] = v;
        }
#pragma unroll
        for (int rr = 0; rr < 4; ++rr) {
            int kk = lr + rr * 16;
            *(float4*)&Bs[kk][lk] = *(const float4*)(B + (size_t)(kc + kk) * HDIM + lk);
        }
        __syncthreads();
#pragma unroll 8
        for (int k = 0; k < 64; ++k) {
            float aa[4];
#pragma unroll
            for (int i = 0; i < 4; ++i) aa[i] = As[tr + i][k];
            float4 b0 = *(const float4*)&Bs[k][tc];
            float4 b1 = *(const float4*)&Bs[k][tc + 4];
            float bb[8] = {b0.x, b0.y, b0.z, b0.w, b1.x, b1.y, b1.z, b1.w};
#pragma unroll
            for (int i = 0; i < 4; ++i)
#pragma unroll
                for (int j = 0; j < 8; ++j) acc[i][j] = fmaf(aa[i], bb[j], acc[i][j]);
        }
        __syncthreads();
    }
#pragma unroll
    for (int i = 0; i < 4; ++i) {
        int grow = row0 + tr + i;
        if (grow < n) {
            *(float4*)(C + (size_t)grow * HDIM + tc) =
                make_float4(acc[i][0], acc[i][1], acc[i][2], acc[i][3]);
            *(float4*)(C + (size_t)grow * HDIM + tc + 4) =
                make_float4(acc[i][4], acc[i][5], acc[i][6], acc[i][7]);
        }
    }
}

// ---------------- pull-style aggregation + self-loop + bias + relu ----------------
// 16 lanes per node, each owns a float4 of the 64-wide feature row.
__global__ __launch_bounds__(256) void k_gather(const float* __restrict__ h,
                                                const int* __restrict__ off,
                                                const int* __restrict__ degi,
                                                const int2* __restrict__ eadj,
                                                const float* __restrict__ selfn,
                                                const float* __restrict__ bias,
                                                float* __restrict__ out, int n) {
    int t = blockIdx.x * 256 + threadIdx.x;
    int i = t >> 4;
    if (i >= n) return;
    int q = (t & 15) * 4;
    int e0 = off[i];
    int e1 = e0 + degi[i];
    float ax = 0.f, ay = 0.f, az = 0.f, aw = 0.f;
    float bx = 0.f, by = 0.f, bz = 0.f, bw = 0.f;
    int e = e0;
    for (; e + 1 < e1; e += 2) {       // unroll x2: two row loads in flight
        int2 p0 = eadj[e];
        int2 p1 = eadj[e + 1];
        float4 v0 = *(const float4*)(h + (size_t)p0.x * HDIM + q);
        float4 v1 = *(const float4*)(h + (size_t)p1.x * HDIM + q);
        float w0 = __int_as_float(p0.y);
        float w1 = __int_as_float(p1.y);
        ax = fmaf(v0.x, w0, ax); ay = fmaf(v0.y, w0, ay);
        az = fmaf(v0.z, w0, az); aw = fmaf(v0.w, w0, aw);
        bx = fmaf(v1.x, w1, bx); by = fmaf(v1.y, w1, by);
        bz = fmaf(v1.z, w1, bz); bw = fmaf(v1.w, w1, bw);
    }
    if (e < e1) {
        int2 p0 = eadj[e];
        float4 v0 = *(const float4*)(h + (size_t)p0.x * HDIM + q);
        float w0 = __int_as_float(p0.y);
        ax = fmaf(v0.x, w0, ax); ay = fmaf(v0.y, w0, ay);
        az = fmaf(v0.z, w0, az); aw = fmaf(v0.w, w0, aw);
    }
    ax += bx; ay += by; az += bz; aw += bw;
    float sn = selfn[i];
    float4 hv = *(const float4*)(h + (size_t)i * HDIM + q);
    float4 b = *(const float4*)(bias + q);
    ax = fmaf(hv.x, sn, ax) + b.x;
    ay = fmaf(hv.y, sn, ay) + b.y;
    az = fmaf(hv.z, sn, az) + b.z;
    aw = fmaf(hv.w, sn, aw) + b.w;
    *(float4*)(out + (size_t)i * HDIM + q) =
        make_float4(fmaxf(ax, 0.f), fmaxf(ay, 0.f), fmaxf(az, 0.f), fmaxf(aw, 0.f));
}

// ---------------- pool phase 1: partial sums, 8 segments per graph ----------------
__global__ __launch_bounds__(256) void k_pool_acc(const float* __restrict__ h,
                                                  const int* __restrict__ batch,
                                                  float* __restrict__ pooled, int n) {
    __shared__ float part[4][64];
    int g = blockIdx.x >> 3;
    int seg = blockIdx.x & 7;
    int t = threadIdx.x;
    int f = t & 63;
    int rg = t >> 6;
    // graph bounds via binary search on sorted batch
    int lo = 0, hi = n;
    while (lo < hi) { int m = (lo + hi) >> 1; if (batch[m] < g) lo = m + 1; else hi = m; }
    int s = lo;
    lo = 0; hi = n;
    while (lo < hi) { int m = (lo + hi) >> 1; if (batch[m] < g + 1) lo = m + 1; else hi = m; }
    int e2 = lo;
    int len = e2 - s;
    int chunk = (len + 7) >> 3;
    int i0 = s + seg * chunk;
    int i1 = min(i0 + chunk, e2);

    float sum = 0.f;
    for (int i = i0 + rg; i < i1; i += 4) sum += h[(size_t)i * HDIM + f];
    part[rg][f] = sum;
    __syncthreads();
    if (t < 64) {
        float tot = part[0][t] + part[1][t] + part[2][t] + part[3][t];
        if (tot != 0.f) atomicAdd(&pooled[g * HDIM + t], tot);
    }
}

// ---------------- pool phase 2: mean + linear head ----------------
__global__ __launch_bounds__(640) void k_head(const float* __restrict__ pooled,
                                              const int* __restrict__ batch,
                                              const float* __restrict__ linW,
                                              const float* __restrict__ linb,
                                              float* __restrict__ out, int n) {
    int t = threadIdx.x;
    if (t >= NGRAPH * NCLS) return;
    int g = t / NCLS;
    int c = t - g * NCLS;
    int lo = 0, hi = n;
    while (lo < hi) { int m = (lo + hi) >> 1; if (batch[m] < g) lo = m + 1; else hi = m; }
    int s = lo;
    lo = 0; hi = n;
    while (lo < hi) { int m = (lo + hi) >> 1; if (batch[m] < g + 1) lo = m + 1; else hi = m; }
    float inv = 1.0f / fmaxf((float)(lo - s), 1.0f);
    float acc = linb[c];
#pragma unroll
    for (int k = 0; k < HDIM; ++k)
        acc = fmaf(pooled[g * HDIM + k] * inv, linW[k * NCLS + c], acc);
    out[g * NCLS + c] = acc;
}

extern "C" void kernel_launch(void* const* d_in, const int* in_sizes, int n_in,
                              void* d_out, int out_size, void* d_ws, size_t ws_size,
                              hipStream_t stream) {
    (void)in_sizes; (void)n_in; (void)out_size; (void)ws_size;
    const float* x    = (const float*)d_in[0];
    const int*   ei   = (const int*)d_in[1];
    const int*   batch= (const int*)d_in[2];
    const float* W1   = (const float*)d_in[3];
    const float* b1   = (const float*)d_in[4];
    const float* W2   = (const float*)d_in[5];
    const float* b2   = (const float*)d_in[6];
    const float* W3   = (const float*)d_in[7];
    const float* b3   = (const float*)d_in[8];
    const float* linW = (const float*)d_in[9];
    const float* linb = (const float*)d_in[10];
    float* out = (float*)d_out;

    const int N = N_NODES, E = N_EDGES;
    const int* src = ei;
    const int* dst = ei + E;

    char* ws = (char*)d_ws;
    float* hA     = (float*)ws; ws += (size_t)N * HDIM * 4;
    float* hB     = (float*)ws; ws += (size_t)N * HDIM * 4;
    float* dis    = (float*)ws; ws += (size_t)N * 4;
    float* selfn  = (float*)ws; ws += (size_t)N * 4;
    int2*  eadj   = (int2*)ws;  ws += (size_t)E * 8;
    int*   degi   = (int*)ws;   ws += (size_t)N * 4;
    int*   off    = (int*)ws;   ws += (size_t)N * 4;
    int*   cur    = (int*)ws;   ws += (size_t)N * 4;
    float* pooled = (float*)ws; ws += (size_t)NGRAPH * HDIM * 4;
    int*   bsum   = (int*)ws;   ws += 256 * 4;

    const int nbN = (N + 255) / 256;   // 196
    const int nbE = (E + 255) / 256;   // 3125
    const int gb  = (N + 127) / 128;   // 391
    const int ngth = (N * 16 + 255) / 256;

    hipMemsetAsync(degi, 0, (size_t)N * 4, stream);
    hipMemsetAsync(pooled, 0, (size_t)NGRAPH * HDIM * 4, stream);
    k_deg_count<<<nbE, 256, 0, stream>>>(dst, degi, E);
    k_scan1<<<nbN, 256, 0, stream>>>(degi, off, bsum, N);
    k_scan2<<<1, 256, 0, stream>>>(bsum, nbN);
    k_scan3<<<nbN, 256, 0, stream>>>(off, cur, bsum, degi, dis, selfn, N);
    k_fill<<<nbE, 256, 0, stream>>>(src, dst, dis, cur, eadj, E);

    // layer 1
    k_gemm<F_INPUT><<<gb, 256, 0, stream>>>(x, W1, hA, N);
    k_gather<<<ngth, 256, 0, stream>>>(hA, off, degi, eadj, selfn, b1, hB, N);
    // layer 2
    k_gemm<HDIM><<<gb, 256, 0, stream>>>(hB, W2, hA, N);
    k_gather<<<ngth, 256, 0, stream>>>(hA, off, degi, eadj, selfn, b2, hB, N);
    // layer 3
    k_gemm<HDIM><<<gb, 256, 0, stream>>>(hB, W3, hA, N);
    k_gather<<<ngth, 256, 0, stream>>>(hA, off, degi, eadj, selfn, b3, hB, N);
    // pool + head
    k_pool_acc<<<NGRAPH * 8, 256, 0, stream>>>(hB, batch, pooled, N);
    k_head<<<1, 640, 0, stream>>>(pooled, batch, linW, linb, out, N);
}